// Round 1
// baseline (518.201 us; speedup 1.0000x reference)
//
#include <hip/hip_runtime.h>

typedef __bf16 bf16_t;
typedef __bf16 bf16x8 __attribute__((ext_vector_type(8)));
typedef __bf16 bf16x4 __attribute__((ext_vector_type(4)));
typedef float f32x4 __attribute__((ext_vector_type(4)));

#define MFMA16(a, b, c) __builtin_amdgcn_mfma_f32_16x16x32_bf16((a), (b), (c), 0, 0, 0)

__device__ __forceinline__ void gload_lds16(const void* g, void* l) {
  __builtin_amdgcn_global_load_lds(
      (__attribute__((address_space(1))) void*)(g),
      (__attribute__((address_space(3))) void*)(l), 16, 0, 0);
}

// ---------------- fp32 -> bf16 conversion ----------------
__global__ __launch_bounds__(256) void cvt_f32_bf16(const float* __restrict__ in,
                                                    bf16_t* __restrict__ out, int n4) {
  int i = blockIdx.x * 256 + threadIdx.x;
  if (i >= n4) return;
  float4 v = ((const float4*)in)[i];
  bf16x4 o;
  o[0] = (bf16_t)v.x; o[1] = (bf16_t)v.y; o[2] = (bf16_t)v.z; o[3] = (bf16_t)v.w;
  ((bf16x4*)out)[i] = o;
}

// ---------------- bf16 GEMM, C = A * Bw^T (+bias), 128x128 tile ----------------
// EPI=0: QKV epilogue -> scatter to Q (scaled), K (head-major), V^T (d-major), all bf16
// EPI=1: dense epilogue -> fp32 out row-major
template <int EPI>
__global__ __launch_bounds__(256) void gemm_bt(
    const bf16_t* __restrict__ A, const bf16_t* __restrict__ Bw,
    const float* __restrict__ bias,
    void* __restrict__ o0, void* __restrict__ o1, void* __restrict__ o2,
    int M, int N, int K) {
  __shared__ __attribute__((aligned(16))) bf16_t As[128][32];
  __shared__ __attribute__((aligned(16))) bf16_t Bs[128][32];
  const int tid = threadIdx.x;
  const int lane = tid & 63, wave = tid >> 6;
  const int wr = (wave >> 1) * 64, wc = (wave & 1) * 64;
  const int l15 = lane & 15, l4 = lane >> 4;
  const int bm = blockIdx.y * 128, bn = blockIdx.x * 128;

  f32x4 acc[4][4];
#pragma unroll
  for (int i = 0; i < 4; ++i)
#pragma unroll
    for (int j = 0; j < 4; ++j)
#pragma unroll
      for (int r = 0; r < 4; ++r) acc[i][j][r] = 0.0f;

  const int r0 = tid >> 2;
  const int co = (tid & 3) * 8;
  const bf16_t* gA = A + (size_t)(bm + r0) * K + co;
  const bf16_t* gB = Bw + (size_t)(bn + r0) * K + co;

  for (int kk = 0; kk < K; kk += 32) {
    gload_lds16(gA + kk, &As[r0][co]);
    gload_lds16(gA + kk + (size_t)64 * K, &As[r0 + 64][co]);
    gload_lds16(gB + kk, &Bs[r0][co]);
    gload_lds16(gB + kk + (size_t)64 * K, &Bs[r0 + 64][co]);
    asm volatile("s_waitcnt vmcnt(0)" ::: "memory");
    __syncthreads();
    bf16x8 a[4], b[4];
#pragma unroll
    for (int i = 0; i < 4; ++i) a[i] = *(const bf16x8*)(&As[wr + i * 16 + l15][l4 * 8]);
#pragma unroll
    for (int j = 0; j < 4; ++j) b[j] = *(const bf16x8*)(&Bs[wc + j * 16 + l15][l4 * 8]);
#pragma unroll
    for (int i = 0; i < 4; ++i)
#pragma unroll
      for (int j = 0; j < 4; ++j) acc[i][j] = MFMA16(a[i], b[j], acc[i][j]);
    __syncthreads();
  }

  if (EPI == 0) {
    bf16_t* qb = (bf16_t*)o0;
    bf16_t* kb = (bf16_t*)o1;
    bf16_t* vtb = (bf16_t*)o2;
    const int which = bn >> 11;          // 0=q 1=k 2=v (N-tile uniform)
    const int head = (bn & 2047) >> 7;   // uniform per block
#pragma unroll
    for (int i = 0; i < 4; ++i)
#pragma unroll
      for (int j = 0; j < 4; ++j)
#pragma unroll
        for (int r = 0; r < 4; ++r) {
          int m = bm + wr + i * 16 + l4 * 4 + r;  // row: b*2048 + s
          int n = bn + wc + j * 16 + l15;
          float v = acc[i][j][r] + bias[n];
          int b = m >> 11, s = m & 2047;
          int d = n & 127;
          size_t hb = (size_t)(b * 16 + head);
          if (which == 0) {
            v *= 0.08838834764831845f;  // 1/sqrt(128)
            qb[(hb * 2048 + s) * 128 + d] = (bf16_t)v;
          } else if (which == 1) {
            kb[(hb * 2048 + s) * 128 + d] = (bf16_t)v;
          } else {
            vtb[(hb * 128 + d) * 2048 + s] = (bf16_t)v;
          }
        }
  } else {
    float* O = (float*)o0;
#pragma unroll
    for (int i = 0; i < 4; ++i)
#pragma unroll
      for (int j = 0; j < 4; ++j)
#pragma unroll
        for (int r = 0; r < 4; ++r) {
          int m = bm + wr + i * 16 + l4 * 4 + r;
          int n = bn + wc + j * 16 + l15;
          O[(size_t)m * N + n] = acc[i][j][r] + bias[n];
        }
  }
}

// ---------------- causal flash attention ----------------
// grid (qt, head_blk). 4 waves, each owns 16 q-rows of a 64-row Q tile.
// K LDS [64][128] and V^T LDS [128][64] chunk-XOR swizzled (source-side).
__global__ __launch_bounds__(256) void attn_kernel(
    const bf16_t* __restrict__ qbuf, const bf16_t* __restrict__ kbuf,
    const bf16_t* __restrict__ vtbuf, bf16_t* __restrict__ ctx) {
  __shared__ __attribute__((aligned(16))) bf16_t Ks[64][128];
  __shared__ __attribute__((aligned(16))) bf16_t Vts[128][64];
  __shared__ __attribute__((aligned(16))) bf16_t Ps[4][16][64];

  const int tid = threadIdx.x, lane = tid & 63, w = tid >> 6;
  const int l15 = lane & 15, l4 = lane >> 4;
  const int qt = blockIdx.x, hb = blockIdx.y;
  const int q0 = qt * 64;
  const size_t hoff = (size_t)hb * 2048 * 128;
  const bf16_t* qh = qbuf + hoff;
  const bf16_t* kh = kbuf + hoff;
  const bf16_t* vh = vtbuf + hoff;

  // Q fragments in registers (pre-scaled by 1/sqrt(128) at QKV epilogue)
  bf16x8 qa[4];
#pragma unroll
  for (int ks = 0; ks < 4; ++ks)
    qa[ks] = *(const bf16x8*)(qh + (size_t)(q0 + w * 16 + l15) * 128 + ks * 32 + l4 * 8);

  f32x4 accO[8];
#pragma unroll
  for (int df = 0; df < 8; ++df)
#pragma unroll
    for (int r = 0; r < 4; ++r) accO[df][r] = 0.0f;
  float mrow[4], lrow[4];
#pragma unroll
  for (int r = 0; r < 4; ++r) { mrow[r] = -1e30f; lrow[r] = 0.0f; }

  const int nt = qt + 1;
  for (int t = 0; t < nt; ++t) {
    const int kv0 = t * 64;
    // stage K tile: linear LDS dest, inverse-swizzled global source
#pragma unroll
    for (int it = 0; it < 4; ++it) {
      int c = tid + it * 256;
      int row = c >> 4, slot = c & 15;
      int sch = slot ^ (row & 7);
      gload_lds16(kh + (size_t)(kv0 + row) * 128 + sch * 8, &Ks[row][slot * 8]);
    }
    // stage V^T tile
#pragma unroll
    for (int it = 0; it < 4; ++it) {
      int c = tid + it * 256;
      int row = c >> 3, slot = c & 7;
      int sch = slot ^ (row & 7);
      gload_lds16(vh + (size_t)row * 2048 + kv0 + sch * 8, &Vts[row][slot * 8]);
    }
    asm volatile("s_waitcnt vmcnt(0)" ::: "memory");
    __syncthreads();

    // scores: S = Q * K^T  (rows=q, cols=kv)
    f32x4 sc[4];
#pragma unroll
    for (int nf = 0; nf < 4; ++nf) {
#pragma unroll
      for (int r = 0; r < 4; ++r) sc[nf][r] = 0.0f;
      int row = nf * 16 + l15;
#pragma unroll
      for (int ks = 0; ks < 4; ++ks) {
        int ch = (ks * 4 + l4) ^ (row & 7);
        bf16x8 kf = *(const bf16x8*)(&Ks[row][ch * 8]);
        sc[nf] = MFMA16(qa[ks], kf, sc[nf]);
      }
    }

    // causal mask only on the diagonal tile
    if (t == nt - 1) {
#pragma unroll
      for (int nf = 0; nf < 4; ++nf)
#pragma unroll
        for (int r = 0; r < 4; ++r) {
          int qi = q0 + w * 16 + l4 * 4 + r;
          int kv = kv0 + nf * 16 + l15;
          if (kv > qi) sc[nf][r] = -1e30f;
        }
    }

    // online softmax (fp32); row lives on 16 lanes sharing l4
    float tmax[4], rsum[4], scl[4];
#pragma unroll
    for (int r = 0; r < 4; ++r)
      tmax[r] = fmaxf(fmaxf(sc[0][r], sc[1][r]), fmaxf(sc[2][r], sc[3][r]));
#pragma unroll
    for (int msk = 1; msk <= 8; msk <<= 1)
#pragma unroll
      for (int r = 0; r < 4; ++r)
        tmax[r] = fmaxf(tmax[r], __shfl_xor(tmax[r], msk, 64));
#pragma unroll
    for (int r = 0; r < 4; ++r) {
      float mn = fmaxf(mrow[r], tmax[r]);
      scl[r] = __expf(mrow[r] - mn);
      mrow[r] = mn;
      float s0 = 0.0f;
#pragma unroll
      for (int nf = 0; nf < 4; ++nf) {
        float p = __expf(sc[nf][r] - mn);
        sc[nf][r] = p;
        s0 += p;
      }
      rsum[r] = s0;
    }
#pragma unroll
    for (int msk = 1; msk <= 8; msk <<= 1)
#pragma unroll
      for (int r = 0; r < 4; ++r) rsum[r] += __shfl_xor(rsum[r], msk, 64);
#pragma unroll
    for (int r = 0; r < 4; ++r) lrow[r] = lrow[r] * scl[r] + rsum[r];
#pragma unroll
    for (int df = 0; df < 8; ++df)
#pragma unroll
      for (int r = 0; r < 4; ++r) accO[df][r] *= scl[r];

    // P -> LDS (bf16, chunk-XOR swizzled per row)
#pragma unroll
    for (int nf = 0; nf < 4; ++nf)
#pragma unroll
      for (int r = 0; r < 4; ++r) {
        int qi = l4 * 4 + r;
        int kv = nf * 16 + l15;
        int ch = (kv >> 3) ^ (qi & 7);
        Ps[w][qi][ch * 8 + (kv & 7)] = (bf16_t)sc[nf][r];
      }

    // PV: ctx += P * V
    bf16x8 pa[2];
#pragma unroll
    for (int k2 = 0; k2 < 2; ++k2) {
      int ch = (k2 * 4 + l4) ^ (l15 & 7);
      pa[k2] = *(const bf16x8*)(&Ps[w][l15][ch * 8]);
    }
#pragma unroll
    for (int df = 0; df < 8; ++df) {
      int row = df * 16 + l15;
#pragma unroll
      for (int k2 = 0; k2 < 2; ++k2) {
        int ch = (k2 * 4 + l4) ^ (row & 7);
        bf16x8 vf = *(const bf16x8*)(&Vts[row][ch * 8]);
        accO[df] = MFMA16(pa[k2], vf, accO[df]);
      }
    }
    __syncthreads();
  }

  // epilogue: ctx[b*2048+s][head*128+d] = accO / l
  const int b = hb >> 4, head = hb & 15;
  float inv[4];
#pragma unroll
  for (int r = 0; r < 4; ++r) inv[r] = 1.0f / lrow[r];
#pragma unroll
  for (int df = 0; df < 8; ++df)
#pragma unroll
    for (int r = 0; r < 4; ++r) {
      int s = q0 + w * 16 + l4 * 4 + r;
      int col = head * 128 + df * 16 + l15;
      ctx[((size_t)(b * 2048 + s)) * 2048 + col] = (bf16_t)(accO[df][r] * inv[r]);
    }
}

extern "C" void kernel_launch(void* const* d_in, const int* in_sizes, int n_in,
                              void* d_out, int out_size, void* d_ws, size_t ws_size,
                              hipStream_t stream) {
  const float* hs = (const float*)d_in[0];
  // d_in[1] = ltor_mask (guaranteed causal tril; handled analytically)
  const float* w_qkv = (const float*)d_in[2];
  const float* b_qkv = (const float*)d_in[3];
  const float* w_dense = (const float*)d_in[4];
  const float* b_dense = (const float*)d_in[5];
  float* out = (float*)d_out;

  const size_t SZ_HS = (size_t)4096 * 2048;     // 8.39M
  const size_t SZ_WQKV = (size_t)6144 * 2048;   // 12.58M
  const size_t SZ_WD = (size_t)2048 * 2048;     // 4.19M
  const size_t SZ_H = (size_t)32 * 2048 * 128;  // per Q/K/Vt buffer

  char* ws = (char*)d_ws;
  bf16_t* A_ = (bf16_t*)ws;                          // hs_bf, later wdense_bf
  bf16_t* B_ = (bf16_t*)(ws + 2 * SZ_HS);            // wqkv_bf, later ctx
  bf16_t* Q_ = (bf16_t*)(ws + 2 * (SZ_HS + SZ_WQKV));
  bf16_t* K_ = Q_ + SZ_H;
  bf16_t* V_ = K_ + SZ_H;

  cvt_f32_bf16<<<(int)(SZ_HS / 4 / 256), 256, 0, stream>>>(hs, A_, (int)(SZ_HS / 4));
  cvt_f32_bf16<<<(int)(SZ_WQKV / 4 / 256), 256, 0, stream>>>(w_qkv, B_, (int)(SZ_WQKV / 4));

  gemm_bt<0><<<dim3(48, 32), 256, 0, stream>>>(A_, B_, b_qkv, Q_, K_, V_, 4096, 6144, 2048);

  cvt_f32_bf16<<<(int)(SZ_WD / 4 / 256), 256, 0, stream>>>(w_dense, A_, (int)(SZ_WD / 4));

  attn_kernel<<<dim3(32, 32), 256, 0, stream>>>(Q_, K_, V_, B_);

  gemm_bt<1><<<dim3(16, 32), 256, 0, stream>>>(B_, A_, b_dense, out, nullptr, nullptr,
                                               4096, 2048, 2048);
}

// Round 5
// 461.848 us; speedup vs baseline: 1.1220x; 1.1220x over previous
//
#include <hip/hip_runtime.h>

typedef __bf16 bf16_t;
typedef __bf16 bf16x8 __attribute__((ext_vector_type(8)));
typedef __bf16 bf16x4 __attribute__((ext_vector_type(4)));
typedef float f32x4 __attribute__((ext_vector_type(4)));

#define MFMA16(a, b, c) __builtin_amdgcn_mfma_f32_16x16x32_bf16((a), (b), (c), 0, 0, 0)

__device__ __forceinline__ void gload_lds16(const void* g, void* l) {
  __builtin_amdgcn_global_load_lds(
      (__attribute__((address_space(1))) void*)(g),
      (__attribute__((address_space(3))) void*)(l), 16, 0, 0);
}

__device__ __forceinline__ void block_bar() {
  asm volatile("" ::: "memory");
  __builtin_amdgcn_s_barrier();
  asm volatile("" ::: "memory");
}

// ---------------- fp32 -> bf16 conversion ----------------
__global__ __launch_bounds__(256) void cvt_f32_bf16(const float* __restrict__ in,
                                                    bf16_t* __restrict__ out, int n4) {
  int i = blockIdx.x * 256 + threadIdx.x;
  if (i >= n4) return;
  float4 v = ((const float4*)in)[i];
  bf16x4 o;
  o[0] = (bf16_t)v.x; o[1] = (bf16_t)v.y; o[2] = (bf16_t)v.z; o[3] = (bf16_t)v.w;
  ((bf16x4*)out)[i] = o;
}

// ---------------- bf16 GEMM, C = A * Bw^T (+bias), 128x128 tile ----------------
template <int EPI>
__global__ __launch_bounds__(256) void gemm_bt(
    const bf16_t* __restrict__ A, const bf16_t* __restrict__ Bw,
    const float* __restrict__ bias,
    void* __restrict__ o0, void* __restrict__ o1, void* __restrict__ o2,
    int M, int N, int K) {
  __shared__ __attribute__((aligned(16))) bf16_t As[128][32];
  __shared__ __attribute__((aligned(16))) bf16_t Bs[128][32];
  const int tid = threadIdx.x;
  const int lane = tid & 63, wave = tid >> 6;
  const int wr = (wave >> 1) * 64, wc = (wave & 1) * 64;
  const int l15 = lane & 15, l4 = lane >> 4;
  const int bm = blockIdx.y * 128, bn = blockIdx.x * 128;

  f32x4 acc[4][4];
#pragma unroll
  for (int i = 0; i < 4; ++i)
#pragma unroll
    for (int j = 0; j < 4; ++j)
#pragma unroll
      for (int r = 0; r < 4; ++r) acc[i][j][r] = 0.0f;

  const int r0 = tid >> 2;
  const int co = (tid & 3) * 8;
  const bf16_t* gA = A + (size_t)(bm + r0) * K + co;
  const bf16_t* gB = Bw + (size_t)(bn + r0) * K + co;

  for (int kk = 0; kk < K; kk += 32) {
    gload_lds16(gA + kk, &As[r0][co]);
    gload_lds16(gA + kk + (size_t)64 * K, &As[r0 + 64][co]);
    gload_lds16(gB + kk, &Bs[r0][co]);
    gload_lds16(gB + kk + (size_t)64 * K, &Bs[r0 + 64][co]);
    asm volatile("s_waitcnt vmcnt(0)" ::: "memory");
    __syncthreads();
    bf16x8 a[4], b[4];
#pragma unroll
    for (int i = 0; i < 4; ++i) a[i] = *(const bf16x8*)(&As[wr + i * 16 + l15][l4 * 8]);
#pragma unroll
    for (int j = 0; j < 4; ++j) b[j] = *(const bf16x8*)(&Bs[wc + j * 16 + l15][l4 * 8]);
#pragma unroll
    for (int i = 0; i < 4; ++i)
#pragma unroll
      for (int j = 0; j < 4; ++j) acc[i][j] = MFMA16(a[i], b[j], acc[i][j]);
    __syncthreads();
  }

  if (EPI == 0) {
    bf16_t* qb = (bf16_t*)o0;
    bf16_t* kb = (bf16_t*)o1;
    bf16_t* vtb = (bf16_t*)o2;
    const int which = bn >> 11;
    const int head = (bn & 2047) >> 7;
#pragma unroll
    for (int i = 0; i < 4; ++i)
#pragma unroll
      for (int j = 0; j < 4; ++j)
#pragma unroll
        for (int r = 0; r < 4; ++r) {
          int m = bm + wr + i * 16 + l4 * 4 + r;
          int n = bn + wc + j * 16 + l15;
          float v = acc[i][j][r] + bias[n];
          int b = m >> 11, s = m & 2047;
          int d = n & 127;
          size_t hb = (size_t)(b * 16 + head);
          if (which == 0) {
            v *= 0.08838834764831845f;  // 1/sqrt(128)
            qb[(hb * 2048 + s) * 128 + d] = (bf16_t)v;
          } else if (which == 1) {
            kb[(hb * 2048 + s) * 128 + d] = (bf16_t)v;
          } else {
            vtb[(hb * 128 + d) * 2048 + s] = (bf16_t)v;
          }
        }
  } else {
    float* O = (float*)o0;
#pragma unroll
    for (int i = 0; i < 4; ++i)
#pragma unroll
      for (int j = 0; j < 4; ++j)
#pragma unroll
        for (int r = 0; r < 4; ++r) {
          int m = bm + wr + i * 16 + l4 * 4 + r;
          int n = bn + wc + j * 16 + l15;
          O[(size_t)m * N + n] = acc[i][j][r] + bias[n];
        }
  }
}

// ---------------- causal flash attention, v2 ----------------
// grid (8, 32): block bx handles Q-tiles (bx, 15-bx) of 128 rows -> uniform 34
// KV-tile-steps/block. 8 waves x 16 q-rows. K/V double-buffered in LDS with
// counted vmcnt prefetch; chunk-XOR swizzle (source-side) on K and V^T.
__global__ __launch_bounds__(512) void attn_kernel(
    const bf16_t* __restrict__ qbuf, const bf16_t* __restrict__ kbuf,
    const bf16_t* __restrict__ vtbuf, bf16_t* __restrict__ ctx) {
  __shared__ __attribute__((aligned(16))) bf16_t Ks[2][64][128];
  __shared__ __attribute__((aligned(16))) bf16_t Vts[2][128][64];
  __shared__ __attribute__((aligned(16))) bf16_t Ps[8][16][64];

  const int tid = threadIdx.x, lane = tid & 63, w = tid >> 6;
  const int l15 = lane & 15, l4 = lane >> 4;
  const int hb = blockIdx.y;
  const size_t hoff = (size_t)hb * 2048 * 128;
  const bf16_t* qh = qbuf + hoff;
  const bf16_t* kh = kbuf + hoff;
  const bf16_t* vh = vtbuf + hoff;
  const int b = hb >> 4, head = hb & 15;

  // staging decomposition (512 threads, 2 chunks each for K and V)
  const int kr0 = tid >> 4, ks0 = tid & 15;          // K: +row 32/iter
  const int vr0 = tid >> 3, vs0 = tid & 7;           // V: +row 64/iter

  int buf = 0;

#pragma unroll 1
  for (int phase = 0; phase < 2; ++phase) {
    const int qt = phase == 0 ? blockIdx.x : 15 - blockIdx.x;
    const int q0 = qt * 128;
    const int nt = 2 * qt + 2;

    // Q fragments (pre-scaled by 1/sqrt(128))
    bf16x8 qa[4];
#pragma unroll
    for (int ks = 0; ks < 4; ++ks)
      qa[ks] = *(const bf16x8*)(qh + (size_t)(q0 + w * 16 + l15) * 128 + ks * 32 + l4 * 8);

    f32x4 accO[8];
#pragma unroll
    for (int df = 0; df < 8; ++df)
#pragma unroll
      for (int r = 0; r < 4; ++r) accO[df][r] = 0.0f;
    float mrow[4], lrow[4];
#pragma unroll
    for (int r = 0; r < 4; ++r) { mrow[r] = -1e30f; lrow[r] = 0.0f; }

    // prologue: stage tile 0 into buf
    {
      const int kv0 = 0;
#pragma unroll
      for (int it = 0; it < 2; ++it) {
        int row = kr0 + it * 32, sch = ks0 ^ (row & 7);
        gload_lds16(kh + (size_t)(kv0 + row) * 128 + sch * 8, &Ks[buf][row][ks0 * 8]);
      }
#pragma unroll
      for (int it = 0; it < 2; ++it) {
        int row = vr0 + it * 64, sch = vs0 ^ (row & 7);
        gload_lds16(vh + (size_t)row * 2048 + kv0 + sch * 8, &Vts[buf][row][vs0 * 8]);
      }
    }

#pragma unroll 1
    for (int t = 0; t < nt; ++t) {
      const int kv0 = t * 64;
      if (t + 1 < nt) {
        const int kvn = (t + 1) * 64;
        const int nb = buf ^ 1;
#pragma unroll
        for (int it = 0; it < 2; ++it) {
          int row = kr0 + it * 32, sch = ks0 ^ (row & 7);
          gload_lds16(kh + (size_t)(kvn + row) * 128 + sch * 8, &Ks[nb][row][ks0 * 8]);
        }
#pragma unroll
        for (int it = 0; it < 2; ++it) {
          int row = vr0 + it * 64, sch = vs0 ^ (row & 7);
          gload_lds16(vh + (size_t)row * 2048 + kvn + sch * 8, &Vts[nb][row][vs0 * 8]);
        }
        asm volatile("s_waitcnt vmcnt(4)" ::: "memory");
      } else {
        asm volatile("s_waitcnt vmcnt(0)" ::: "memory");
      }
      block_bar();

      const bool active = (kv0 <= q0 + w * 16 + 15);
      if (active) {
        // S = Q * K^T
        f32x4 sc[4];
#pragma unroll
        for (int nf = 0; nf < 4; ++nf) {
#pragma unroll
          for (int r = 0; r < 4; ++r) sc[nf][r] = 0.0f;
          int row = nf * 16 + l15;
#pragma unroll
          for (int ks = 0; ks < 4; ++ks) {
            int ch = (ks * 4 + l4) ^ (row & 7);
            bf16x8 kf = *(const bf16x8*)(&Ks[buf][row][ch * 8]);
            sc[nf] = MFMA16(qa[ks], kf, sc[nf]);
          }
        }

        // causal mask (only waves straddling the diagonal)
        if (kv0 + 63 > q0 + w * 16) {
#pragma unroll
          for (int nf = 0; nf < 4; ++nf)
#pragma unroll
            for (int r = 0; r < 4; ++r) {
              int qi = q0 + w * 16 + l4 * 4 + r;
              int kv = kv0 + nf * 16 + l15;
              if (kv > qi) sc[nf][r] = -1e30f;
            }
        }

        // online softmax with defer-max (THR=8)
        float tmax[4];
#pragma unroll
        for (int r = 0; r < 4; ++r)
          tmax[r] = fmaxf(fmaxf(sc[0][r], sc[1][r]), fmaxf(sc[2][r], sc[3][r]));
#pragma unroll
        for (int msk = 1; msk <= 8; msk <<= 1)
#pragma unroll
          for (int r = 0; r < 4; ++r)
            tmax[r] = fmaxf(tmax[r], __shfl_xor(tmax[r], msk, 64));

        bool defer = __all(tmax[0] <= mrow[0] + 8.0f && tmax[1] <= mrow[1] + 8.0f &&
                           tmax[2] <= mrow[2] + 8.0f && tmax[3] <= mrow[3] + 8.0f);
        if (!defer) {
          float scl[4];
#pragma unroll
          for (int r = 0; r < 4; ++r) {
            float mn = fmaxf(mrow[r], tmax[r]);
            scl[r] = __expf(mrow[r] - mn);
            mrow[r] = mn;
            lrow[r] *= scl[r];
          }
#pragma unroll
          for (int df = 0; df < 8; ++df)
#pragma unroll
            for (int r = 0; r < 4; ++r) accO[df][r] *= scl[r];
        }

        float rsum[4];
#pragma unroll
        for (int r = 0; r < 4; ++r) {
          float s0 = 0.0f;
#pragma unroll
          for (int nf = 0; nf < 4; ++nf) {
            float p = __expf(sc[nf][r] - mrow[r]);
            sc[nf][r] = p;
            s0 += p;
          }
          rsum[r] = s0;
        }
#pragma unroll
        for (int msk = 1; msk <= 8; msk <<= 1)
#pragma unroll
          for (int r = 0; r < 4; ++r) rsum[r] += __shfl_xor(rsum[r], msk, 64);
#pragma unroll
        for (int r = 0; r < 4; ++r) lrow[r] += rsum[r];

        // P -> LDS (bf16, chunk-XOR swizzled)
#pragma unroll
        for (int nf = 0; nf < 4; ++nf)
#pragma unroll
          for (int r = 0; r < 4; ++r) {
            int qi = l4 * 4 + r;
            int kv = nf * 16 + l15;
            int ch = (kv >> 3) ^ (qi & 7);
            Ps[w][qi][ch * 8 + (kv & 7)] = (bf16_t)sc[nf][r];
          }

        // PV
        bf16x8 pa[2];
#pragma unroll
        for (int k2 = 0; k2 < 2; ++k2) {
          int ch = (k2 * 4 + l4) ^ (l15 & 7);
          pa[k2] = *(const bf16x8*)(&Ps[w][l15][ch * 8]);
        }
#pragma unroll
        for (int df = 0; df < 8; ++df) {
          int row = df * 16 + l15;
#pragma unroll
          for (int k2 = 0; k2 < 2; ++k2) {
            int ch = (k2 * 4 + l4) ^ (row & 7);
            bf16x8 vf = *(const bf16x8*)(&Vts[buf][row][ch * 8]);
            accO[df] = MFMA16(pa[k2], vf, accO[df]);
          }
        }
      }
      block_bar();
      buf ^= 1;
    }

    // epilogue
    float inv[4];
#pragma unroll
    for (int r = 0; r < 4; ++r) inv[r] = 1.0f / lrow[r];
#pragma unroll
    for (int df = 0; df < 8; ++df)
#pragma unroll
      for (int r = 0; r < 4; ++r) {
        int s = q0 + w * 16 + l4 * 4 + r;
        int col = head * 128 + df * 16 + l15;
        ctx[((size_t)(b * 2048 + s)) * 2048 + col] = (bf16_t)(accO[df][r] * inv[r]);
      }
  }
}

extern "C" void kernel_launch(void* const* d_in, const int* in_sizes, int n_in,
                              void* d_out, int out_size, void* d_ws, size_t ws_size,
                              hipStream_t stream) {
  const float* hs = (const float*)d_in[0];
  const float* w_qkv = (const float*)d_in[2];
  const float* b_qkv = (const float*)d_in[3];
  const float* w_dense = (const float*)d_in[4];
  const float* b_dense = (const float*)d_in[5];
  float* out = (float*)d_out;

  const size_t SZ_HS = (size_t)4096 * 2048;
  const size_t SZ_WQKV = (size_t)6144 * 2048;
  const size_t SZ_WD = (size_t)2048 * 2048;
  const size_t SZ_H = (size_t)32 * 2048 * 128;

  char* ws = (char*)d_ws;
  bf16_t* A_ = (bf16_t*)ws;
  bf16_t* B_ = (bf16_t*)(ws + 2 * SZ_HS);
  bf16_t* Q_ = (bf16_t*)(ws + 2 * (SZ_HS + SZ_WQKV));
  bf16_t* K_ = Q_ + SZ_H;
  bf16_t* V_ = K_ + SZ_H;

  cvt_f32_bf16<<<(int)(SZ_HS / 4 / 256), 256, 0, stream>>>(hs, A_, (int)(SZ_HS / 4));
  cvt_f32_bf16<<<(int)(SZ_WQKV / 4 / 256), 256, 0, stream>>>(w_qkv, B_, (int)(SZ_WQKV / 4));

  gemm_bt<0><<<dim3(48, 32), 256, 0, stream>>>(A_, B_, b_qkv, Q_, K_, V_, 4096, 6144, 2048);

  cvt_f32_bf16<<<(int)(SZ_WD / 4 / 256), 256, 0, stream>>>(w_dense, A_, (int)(SZ_WD / 4));

  attn_kernel<<<dim3(8, 32), 512, 0, stream>>>(Q_, K_, V_, B_);

  gemm_bt<1><<<dim3(16, 32), 256, 0, stream>>>(B_, A_, b_dense, out, nullptr, nullptr,
                                               4096, 2048, 2048);
}

// Round 6
// 431.581 us; speedup vs baseline: 1.2007x; 1.0701x over previous
//
#include <hip/hip_runtime.h>

typedef __bf16 bf16_t;
typedef __bf16 bf16x8 __attribute__((ext_vector_type(8)));
typedef __bf16 bf16x4 __attribute__((ext_vector_type(4)));
typedef float f32x4 __attribute__((ext_vector_type(4)));

#define MFMA16(a, b, c) __builtin_amdgcn_mfma_f32_16x16x32_bf16((a), (b), (c), 0, 0, 0)

__device__ __forceinline__ void gload_lds16(const void* g, void* l) {
  __builtin_amdgcn_global_load_lds(
      (__attribute__((address_space(1))) void*)(g),
      (__attribute__((address_space(3))) void*)(l), 16, 0, 0);
}

__device__ __forceinline__ void block_bar() {
  asm volatile("" ::: "memory");
  __builtin_amdgcn_s_barrier();
  asm volatile("" ::: "memory");
}

// ---------------- fp32 -> bf16 conversion ----------------
__global__ __launch_bounds__(256) void cvt_f32_bf16(const float* __restrict__ in,
                                                    bf16_t* __restrict__ out, int n4) {
  int i = blockIdx.x * 256 + threadIdx.x;
  if (i >= n4) return;
  float4 v = ((const float4*)in)[i];
  bf16x4 o;
  o[0] = (bf16_t)v.x; o[1] = (bf16_t)v.y; o[2] = (bf16_t)v.z; o[3] = (bf16_t)v.w;
  ((bf16x4*)out)[i] = o;
}

// ---------------- bf16 GEMM, C = A * Bw^T (+bias), 128x128 tile ----------------
// v2: double-buffered LDS + counted vmcnt prefetch (T3 2-phase recipe):
// issue tile t+1 staging BEFORE compute of tile t; vmcnt(4) leaves the
// prefetch in flight across both barriers. Raw s_barrier (no vmcnt(0) drain).
template <int EPI>
__global__ __launch_bounds__(256) void gemm_bt(
    const bf16_t* __restrict__ A, const bf16_t* __restrict__ Bw,
    const float* __restrict__ bias,
    void* __restrict__ o0, void* __restrict__ o1, void* __restrict__ o2,
    int M, int N, int K) {
  __shared__ __attribute__((aligned(16))) bf16_t As[2][128][32];
  __shared__ __attribute__((aligned(16))) bf16_t Bs[2][128][32];
  const int tid = threadIdx.x;
  const int lane = tid & 63, wave = tid >> 6;
  const int wr = (wave >> 1) * 64, wc = (wave & 1) * 64;
  const int l15 = lane & 15, l4 = lane >> 4;
  const int bm = blockIdx.y * 128, bn = blockIdx.x * 128;

  f32x4 acc[4][4];
#pragma unroll
  for (int i = 0; i < 4; ++i)
#pragma unroll
    for (int j = 0; j < 4; ++j)
#pragma unroll
      for (int r = 0; r < 4; ++r) acc[i][j][r] = 0.0f;

  const int r0 = tid >> 2;
  const int co = (tid & 3) * 8;
  const bf16_t* gA = A + (size_t)(bm + r0) * K + co;
  const bf16_t* gB = Bw + (size_t)(bn + r0) * K + co;

  const int nt = K >> 5;

  // prologue: stage tile 0 into buffer 0
  gload_lds16(gA, &As[0][r0][co]);
  gload_lds16(gA + (size_t)64 * K, &As[0][r0 + 64][co]);
  gload_lds16(gB, &Bs[0][r0][co]);
  gload_lds16(gB + (size_t)64 * K, &Bs[0][r0 + 64][co]);

#pragma unroll 1
  for (int t = 0; t < nt; ++t) {
    const int cb = t & 1;
    if (t + 1 < nt) {
      const int kk = (t + 1) << 5;
      const int nb = cb ^ 1;
      gload_lds16(gA + kk, &As[nb][r0][co]);
      gload_lds16(gA + kk + (size_t)64 * K, &As[nb][r0 + 64][co]);
      gload_lds16(gB + kk, &Bs[nb][r0][co]);
      gload_lds16(gB + kk + (size_t)64 * K, &Bs[nb][r0 + 64][co]);
      asm volatile("s_waitcnt vmcnt(4)" ::: "memory");  // tile t done; t+1 in flight
    } else {
      asm volatile("s_waitcnt vmcnt(0)" ::: "memory");
    }
    block_bar();
    bf16x8 a[4], b[4];
#pragma unroll
    for (int i = 0; i < 4; ++i) a[i] = *(const bf16x8*)(&As[cb][wr + i * 16 + l15][l4 * 8]);
#pragma unroll
    for (int j = 0; j < 4; ++j) b[j] = *(const bf16x8*)(&Bs[cb][wc + j * 16 + l15][l4 * 8]);
#pragma unroll
    for (int i = 0; i < 4; ++i)
#pragma unroll
      for (int j = 0; j < 4; ++j) acc[i][j] = MFMA16(a[i], b[j], acc[i][j]);
    block_bar();  // protect buffer cb^1 (read at t-1) until all waves pass
  }

  if (EPI == 0) {
    bf16_t* qb = (bf16_t*)o0;
    bf16_t* kb = (bf16_t*)o1;
    bf16_t* vtb = (bf16_t*)o2;
    const int which = bn >> 11;
    const int head = (bn & 2047) >> 7;
#pragma unroll
    for (int i = 0; i < 4; ++i)
#pragma unroll
      for (int j = 0; j < 4; ++j)
#pragma unroll
        for (int r = 0; r < 4; ++r) {
          int m = bm + wr + i * 16 + l4 * 4 + r;
          int n = bn + wc + j * 16 + l15;
          float v = acc[i][j][r] + bias[n];
          int b = m >> 11, s = m & 2047;
          int d = n & 127;
          size_t hb = (size_t)(b * 16 + head);
          if (which == 0) {
            v *= 0.08838834764831845f;  // 1/sqrt(128)
            qb[(hb * 2048 + s) * 128 + d] = (bf16_t)v;
          } else if (which == 1) {
            kb[(hb * 2048 + s) * 128 + d] = (bf16_t)v;
          } else {
            vtb[(hb * 128 + d) * 2048 + s] = (bf16_t)v;
          }
        }
  } else {
    float* O = (float*)o0;
#pragma unroll
    for (int i = 0; i < 4; ++i)
#pragma unroll
      for (int j = 0; j < 4; ++j)
#pragma unroll
        for (int r = 0; r < 4; ++r) {
          int m = bm + wr + i * 16 + l4 * 4 + r;
          int n = bn + wc + j * 16 + l15;
          O[(size_t)m * N + n] = acc[i][j][r] + bias[n];
        }
  }
}

// ---------------- causal flash attention, v2 ----------------
// grid (8, 32): block bx handles Q-tiles (bx, 15-bx) of 128 rows -> uniform 34
// KV-tile-steps/block. 8 waves x 16 q-rows. K/V double-buffered in LDS with
// counted vmcnt prefetch; chunk-XOR swizzle (source-side) on K and V^T.
__global__ __launch_bounds__(512) void attn_kernel(
    const bf16_t* __restrict__ qbuf, const bf16_t* __restrict__ kbuf,
    const bf16_t* __restrict__ vtbuf, bf16_t* __restrict__ ctx) {
  __shared__ __attribute__((aligned(16))) bf16_t Ks[2][64][128];
  __shared__ __attribute__((aligned(16))) bf16_t Vts[2][128][64];
  __shared__ __attribute__((aligned(16))) bf16_t Ps[8][16][64];

  const int tid = threadIdx.x, lane = tid & 63, w = tid >> 6;
  const int l15 = lane & 15, l4 = lane >> 4;
  const int hb = blockIdx.y;
  const size_t hoff = (size_t)hb * 2048 * 128;
  const bf16_t* qh = qbuf + hoff;
  const bf16_t* kh = kbuf + hoff;
  const bf16_t* vh = vtbuf + hoff;
  const int b = hb >> 4, head = hb & 15;

  // staging decomposition (512 threads, 2 chunks each for K and V)
  const int kr0 = tid >> 4, ks0 = tid & 15;          // K: +row 32/iter
  const int vr0 = tid >> 3, vs0 = tid & 7;           // V: +row 64/iter

  int buf = 0;

#pragma unroll 1
  for (int phase = 0; phase < 2; ++phase) {
    const int qt = phase == 0 ? blockIdx.x : 15 - blockIdx.x;
    const int q0 = qt * 128;
    const int nt = 2 * qt + 2;

    // Q fragments (pre-scaled by 1/sqrt(128))
    bf16x8 qa[4];
#pragma unroll
    for (int ks = 0; ks < 4; ++ks)
      qa[ks] = *(const bf16x8*)(qh + (size_t)(q0 + w * 16 + l15) * 128 + ks * 32 + l4 * 8);

    f32x4 accO[8];
#pragma unroll
    for (int df = 0; df < 8; ++df)
#pragma unroll
      for (int r = 0; r < 4; ++r) accO[df][r] = 0.0f;
    float mrow[4], lrow[4];
#pragma unroll
    for (int r = 0; r < 4; ++r) { mrow[r] = -1e30f; lrow[r] = 0.0f; }

    // prologue: stage tile 0 into buf
    {
      const int kv0 = 0;
#pragma unroll
      for (int it = 0; it < 2; ++it) {
        int row = kr0 + it * 32, sch = ks0 ^ (row & 7);
        gload_lds16(kh + (size_t)(kv0 + row) * 128 + sch * 8, &Ks[buf][row][ks0 * 8]);
      }
#pragma unroll
      for (int it = 0; it < 2; ++it) {
        int row = vr0 + it * 64, sch = vs0 ^ (row & 7);
        gload_lds16(vh + (size_t)row * 2048 + kv0 + sch * 8, &Vts[buf][row][vs0 * 8]);
      }
    }

#pragma unroll 1
    for (int t = 0; t < nt; ++t) {
      const int kv0 = t * 64;
      if (t + 1 < nt) {
        const int kvn = (t + 1) * 64;
        const int nb = buf ^ 1;
#pragma unroll
        for (int it = 0; it < 2; ++it) {
          int row = kr0 + it * 32, sch = ks0 ^ (row & 7);
          gload_lds16(kh + (size_t)(kvn + row) * 128 + sch * 8, &Ks[nb][row][ks0 * 8]);
        }
#pragma unroll
        for (int it = 0; it < 2; ++it) {
          int row = vr0 + it * 64, sch = vs0 ^ (row & 7);
          gload_lds16(vh + (size_t)row * 2048 + kvn + sch * 8, &Vts[nb][row][vs0 * 8]);
        }
        asm volatile("s_waitcnt vmcnt(4)" ::: "memory");
      } else {
        asm volatile("s_waitcnt vmcnt(0)" ::: "memory");
      }
      block_bar();

      const bool active = (kv0 <= q0 + w * 16 + 15);
      if (active) {
        // S = Q * K^T
        f32x4 sc[4];
#pragma unroll
        for (int nf = 0; nf < 4; ++nf) {
#pragma unroll
          for (int r = 0; r < 4; ++r) sc[nf][r] = 0.0f;
          int row = nf * 16 + l15;
#pragma unroll
          for (int ks = 0; ks < 4; ++ks) {
            int ch = (ks * 4 + l4) ^ (row & 7);
            bf16x8 kf = *(const bf16x8*)(&Ks[buf][row][ch * 8]);
            sc[nf] = MFMA16(qa[ks], kf, sc[nf]);
          }
        }

        // causal mask (only waves straddling the diagonal)
        if (kv0 + 63 > q0 + w * 16) {
#pragma unroll
          for (int nf = 0; nf < 4; ++nf)
#pragma unroll
            for (int r = 0; r < 4; ++r) {
              int qi = q0 + w * 16 + l4 * 4 + r;
              int kv = kv0 + nf * 16 + l15;
              if (kv > qi) sc[nf][r] = -1e30f;
            }
        }

        // online softmax with defer-max (THR=8)
        float tmax[4];
#pragma unroll
        for (int r = 0; r < 4; ++r)
          tmax[r] = fmaxf(fmaxf(sc[0][r], sc[1][r]), fmaxf(sc[2][r], sc[3][r]));
#pragma unroll
        for (int msk = 1; msk <= 8; msk <<= 1)
#pragma unroll
          for (int r = 0; r < 4; ++r)
            tmax[r] = fmaxf(tmax[r], __shfl_xor(tmax[r], msk, 64));

        bool defer = __all(tmax[0] <= mrow[0] + 8.0f && tmax[1] <= mrow[1] + 8.0f &&
                           tmax[2] <= mrow[2] + 8.0f && tmax[3] <= mrow[3] + 8.0f);
        if (!defer) {
          float scl[4];
#pragma unroll
          for (int r = 0; r < 4; ++r) {
            float mn = fmaxf(mrow[r], tmax[r]);
            scl[r] = __expf(mrow[r] - mn);
            mrow[r] = mn;
            lrow[r] *= scl[r];
          }
#pragma unroll
          for (int df = 0; df < 8; ++df)
#pragma unroll
            for (int r = 0; r < 4; ++r) accO[df][r] *= scl[r];
        }

        float rsum[4];
#pragma unroll
        for (int r = 0; r < 4; ++r) {
          float s0 = 0.0f;
#pragma unroll
          for (int nf = 0; nf < 4; ++nf) {
            float p = __expf(sc[nf][r] - mrow[r]);
            sc[nf][r] = p;
            s0 += p;
          }
          rsum[r] = s0;
        }
#pragma unroll
        for (int msk = 1; msk <= 8; msk <<= 1)
#pragma unroll
          for (int r = 0; r < 4; ++r) rsum[r] += __shfl_xor(rsum[r], msk, 64);
#pragma unroll
        for (int r = 0; r < 4; ++r) lrow[r] += rsum[r];

        // P -> LDS (bf16, chunk-XOR swizzled)
#pragma unroll
        for (int nf = 0; nf < 4; ++nf)
#pragma unroll
          for (int r = 0; r < 4; ++r) {
            int qi = l4 * 4 + r;
            int kv = nf * 16 + l15;
            int ch = (kv >> 3) ^ (qi & 7);
            Ps[w][qi][ch * 8 + (kv & 7)] = (bf16_t)sc[nf][r];
          }

        // PV
        bf16x8 pa[2];
#pragma unroll
        for (int k2 = 0; k2 < 2; ++k2) {
          int ch = (k2 * 4 + l4) ^ (l15 & 7);
          pa[k2] = *(const bf16x8*)(&Ps[w][l15][ch * 8]);
        }
#pragma unroll
        for (int df = 0; df < 8; ++df) {
          int row = df * 16 + l15;
#pragma unroll
          for (int k2 = 0; k2 < 2; ++k2) {
            int ch = (k2 * 4 + l4) ^ (row & 7);
            bf16x8 vf = *(const bf16x8*)(&Vts[buf][row][ch * 8]);
            accO[df] = MFMA16(pa[k2], vf, accO[df]);
          }
        }
      }
      block_bar();
      buf ^= 1;
    }

    // epilogue
    float inv[4];
#pragma unroll
    for (int r = 0; r < 4; ++r) inv[r] = 1.0f / lrow[r];
#pragma unroll
    for (int df = 0; df < 8; ++df)
#pragma unroll
      for (int r = 0; r < 4; ++r) {
        int s = q0 + w * 16 + l4 * 4 + r;
        int col = head * 128 + df * 16 + l15;
        ctx[((size_t)(b * 2048 + s)) * 2048 + col] = (bf16_t)(accO[df][r] * inv[r]);
      }
  }
}

extern "C" void kernel_launch(void* const* d_in, const int* in_sizes, int n_in,
                              void* d_out, int out_size, void* d_ws, size_t ws_size,
                              hipStream_t stream) {
  const float* hs = (const float*)d_in[0];
  const float* w_qkv = (const float*)d_in[2];
  const float* b_qkv = (const float*)d_in[3];
  const float* w_dense = (const float*)d_in[4];
  const float* b_dense = (const float*)d_in[5];
  float* out = (float*)d_out;

  const size_t SZ_HS = (size_t)4096 * 2048;
  const size_t SZ_WQKV = (size_t)6144 * 2048;
  const size_t SZ_WD = (size_t)2048 * 2048;
  const size_t SZ_H = (size_t)32 * 2048 * 128;

  char* ws = (char*)d_ws;
  bf16_t* A_ = (bf16_t*)ws;
  bf16_t* B_ = (bf16_t*)(ws + 2 * SZ_HS);
  bf16_t* Q_ = (bf16_t*)(ws + 2 * (SZ_HS + SZ_WQKV));
  bf16_t* K_ = Q_ + SZ_H;
  bf16_t* V_ = K_ + SZ_H;

  cvt_f32_bf16<<<(int)(SZ_HS / 4 / 256), 256, 0, stream>>>(hs, A_, (int)(SZ_HS / 4));
  cvt_f32_bf16<<<(int)(SZ_WQKV / 4 / 256), 256, 0, stream>>>(w_qkv, B_, (int)(SZ_WQKV / 4));

  gemm_bt<0><<<dim3(48, 32), 256, 0, stream>>>(A_, B_, b_qkv, Q_, K_, V_, 4096, 6144, 2048);

  cvt_f32_bf16<<<(int)(SZ_WD / 4 / 256), 256, 0, stream>>>(w_dense, A_, (int)(SZ_WD / 4));

  attn_kernel<<<dim3(8, 32), 512, 0, stream>>>(Q_, K_, V_, B_);

  gemm_bt<1><<<dim3(16, 32), 256, 0, stream>>>(B_, A_, b_dense, out, nullptr, nullptr,
                                               4096, 2048, 2048);
}